// Round 1
// baseline (1265.355 us; speedup 1.0000x reference)
//
#include <hip/hip_runtime.h>

#define B_N   32768
#define HID   512
#define DIM   256
#define MAXN  17
#define SM    264   // SP_MID == KEY_MID
#define DM    384   // DEC_MID

typedef __attribute__((ext_vector_type(8))) short bf16x8;
typedef __attribute__((ext_vector_type(4))) float f32x4;

static __device__ __forceinline__ unsigned short f2bf(float x) {
  union { float f; unsigned u; } v; v.f = x;
  unsigned r = (v.u + 0x7FFFu + ((v.u >> 16) & 1u)) >> 16;   // RNE
  return (unsigned short)r;
}

// ---------------------------------------------------------------------------
// Stage 1: size_pred MLP + argmax.  16 samples / workgroup, 320 threads.
// MUST stay fp32: argmax flips would corrupt the ragged layout.
// v2: W1 streamed from L2 (coalesced float4, no LDS staging, no in-loop
// barriers); z read as wave-broadcast float4; W2 pre-transposed into LDS.
// FMA accumulation order is bit-identical to the verified baseline.
// ---------------------------------------------------------------------------
__global__ __launch_bounds__(320) void sizepred_kernel(
    const float* __restrict__ z,  const float* __restrict__ W1,
    const float* __restrict__ b1, const float* __restrict__ g1,
    const float* __restrict__ be1, const float* __restrict__ W2,
    const float* __restrict__ b2, int* __restrict__ n_out)
{
  __shared__ __align__(16) float us[16 * 268];    // stride 268: f4-aligned, no pow2 bank stride
  __shared__ __align__(16) float w2t[17 * 268];   // W2^T, stride 268
  __shared__ float lnm[16], lnr[16];
  __shared__ float log17[16 * 17];

  const int tid = threadIdx.x;
  const int b0  = blockIdx.x * 16;

  // stage W2^T (used only after the first barrier below)
  for (int idx = tid; idx < 264 * 17; idx += 320) {
    int c = idx / 17, jj = idx - c * 17;
    w2t[jj * 268 + c] = W2[idx];
  }

  const bool act = tid < 264;
  const int  s0  = (tid / 66) * 4;
  const int  j0  = (tid % 66) * 4;

  float acc[4][4];
#pragma unroll
  for (int i = 0; i < 4; ++i)
#pragma unroll
    for (int q = 0; q < 4; ++q) acc[i][q] = 0.f;

  if (act) {
    const float* wp = W1 + j0;
    const float* zp = z + (size_t)(b0 + s0) * 512;
    for (int c0 = 0; c0 < 512; c0 += 8) {
      float a[4][8];
#pragma unroll
      for (int i = 0; i < 4; ++i) {
        float4 lo = *(const float4*)(zp + (size_t)i * 512 + c0);
        float4 hi = *(const float4*)(zp + (size_t)i * 512 + c0 + 4);
        a[i][0] = lo.x; a[i][1] = lo.y; a[i][2] = lo.z; a[i][3] = lo.w;
        a[i][4] = hi.x; a[i][5] = hi.y; a[i][6] = hi.z; a[i][7] = hi.w;
      }
#pragma unroll
      for (int cc = 0; cc < 8; ++cc) {
        float4 bv = *(const float4*)(wp + (size_t)(c0 + cc) * 264);
#pragma unroll
        for (int i = 0; i < 4; ++i) {
          acc[i][0] += a[i][cc] * bv.x;
          acc[i][1] += a[i][cc] * bv.y;
          acc[i][2] += a[i][cc] * bv.z;
          acc[i][3] += a[i][cc] * bv.w;
        }
      }
    }
    float4 bb = *(const float4*)&b1[j0];
#pragma unroll
    for (int i = 0; i < 4; ++i) {
      float4 o;
      o.x = acc[i][0] + bb.x; o.y = acc[i][1] + bb.y;
      o.z = acc[i][2] + bb.z; o.w = acc[i][3] + bb.w;
      *(float4*)&us[(s0 + i) * 268 + j0] = o;
    }
  }
  __syncthreads();

  // LN stats: serial per sample — EXACT summation order of verified baseline.
  if (tid < 16) {
    float s = 0.f, q = 0.f;
    for (int j = 0; j < 264; ++j) { float v = us[tid * 268 + j]; s += v; q += v * v; }
    float m   = s / 264.f;
    float var = q / 264.f - m * m;
    lnm[tid] = m;
    lnr[tid] = 1.f / sqrtf(var + 1e-5f);
  }
  __syncthreads();

  for (int idx = tid; idx < 16 * 264; idx += 320) {
    int s = idx / 264, j = idx - s * 264;
    float v = (us[s * 268 + j] - lnm[s]) * lnr[s] * g1[j] + be1[j];
    us[s * 268 + j] = fmaxf(v, 0.f);
  }
  __syncthreads();

  if (tid < 272) {
    int s = tid / 17, jj = tid - s * 17;
    float a = b2[jj];
    const float* up = &us[s * 268];
    const float* wt = &w2t[jj * 268];
#pragma unroll 4
    for (int c = 0; c < 264; c += 4) {
      float4 u = *(const float4*)(up + c);
      float4 w = *(const float4*)(wt + c);
      a += u.x * w.x; a += u.y * w.y; a += u.z * w.z; a += u.w * w.w;
    }
    log17[tid] = a;
  }
  __syncthreads();

  if (tid < 16) {
    int best = 0; float bv = log17[tid * 17];
    for (int jj = 1; jj < 17; ++jj) {
      float v = log17[tid * 17 + jj];
      if (v > bv) { bv = v; best = jj; }
    }
    n_out[b0 + tid] = best;
  }
}

// ---------------------------------------------------------------------------
// Stage 2: exclusive prefix sum of n[32768] -> starts[32769]. One block.
// ---------------------------------------------------------------------------
__global__ __launch_bounds__(1024) void scan_kernel(const int* __restrict__ n,
                                                    int* __restrict__ starts)
{
  __shared__ int part[1024];
  const int tid  = threadIdx.x;
  const int base = tid * 32;
  int loc[32];
  int s = 0;
#pragma unroll
  for (int i = 0; i < 32; ++i) { loc[i] = n[base + i]; s += loc[i]; }
  part[tid] = s;
  __syncthreads();
  for (int off = 1; off < 1024; off <<= 1) {
    int v   = part[tid];
    int add = (tid >= off) ? part[tid - off] : 0;
    __syncthreads();
    part[tid] = v + add;
    __syncthreads();
  }
  int run = part[tid] - s;
#pragma unroll
  for (int i = 0; i < 32; ++i) { starts[base + i] = run; run += loc[i]; }
  if (tid == 1023) starts[B_N] = run;
}

// ---------------------------------------------------------------------------
// Stage 3: scatter ragged indices + write batch output (as float)
// ---------------------------------------------------------------------------
__global__ __launch_bounds__(256) void scatter_kernel(
    const int* __restrict__ n, const int* __restrict__ starts,
    int* __restrict__ bi, int* __restrict__ ki, float* __restrict__ out, int T)
{
  int b = blockIdx.x * 256 + threadIdx.x;
  if (b >= B_N) return;
  int st = starts[b], nn = n[b];
  float* ob = out + (size_t)T * DIM;
  for (int k = 0; k < nn; ++k) {
    bi[st + k] = b;
    ki[st + k] = k;
    ob[st + k] = (float)b;
  }
}

// ---------------------------------------------------------------------------
// Stage 4: keys table [17][512]
// ---------------------------------------------------------------------------
__global__ __launch_bounds__(320) void keys_kernel(
    const float* __restrict__ W1, const float* __restrict__ b1,
    const float* __restrict__ g1, const float* __restrict__ be1,
    const float* __restrict__ W2, const float* __restrict__ b2,
    float* __restrict__ ktab)
{
  __shared__ float hs[264];
  __shared__ float mr[2];
  const int kk = blockIdx.x, tid = threadIdx.x;
  if (tid < 264) hs[tid] = W1[kk * 264 + tid] + b1[tid];
  __syncthreads();
  if (tid == 0) {
    float s = 0.f, q = 0.f;
    for (int j = 0; j < 264; ++j) { float v = hs[j]; s += v; q += v * v; }
    float m = s / 264.f;
    mr[0] = m;
    mr[1] = 1.f / sqrtf(q / 264.f - m * m + 1e-5f);
  }
  __syncthreads();
  if (tid < 264) hs[tid] = fmaxf((hs[tid] - mr[0]) * mr[1] * g1[tid] + be1[tid], 0.f);
  __syncthreads();
  for (int c = tid; c < 512; c += 320) {
    float a = b2[c];
    for (int j = 0; j < 264; ++j) a += hs[j] * W2[j * 512 + c];
    ktab[kk * 512 + c] = a;
  }
}

// ---------------------------------------------------------------------------
// Stage 4b: pack dec_W1/dec_W2 into bf16 MFMA B-fragment layout.
// Chunk (kt, nt, lane): 8 bf16 = W[kt*32 + (lane>>4)*8 + j][nt*16 + (lane&15)]
// W1p: 16 kt x 24 nt ; W2p: 12 kt x 16 nt.  grid 576 x 64.
// ---------------------------------------------------------------------------
__global__ __launch_bounds__(64) void pack_kernel(
    const float* __restrict__ W1, const float* __restrict__ W2,
    short* __restrict__ W1p, short* __restrict__ W2p)
{
  const int g = blockIdx.x, l = threadIdx.x;
  const float* W; int nt, kt, N;
  if (g < 384) { W = W1; kt = g / 24; nt = g % 24; N = 384; }
  else         { W = W2; int gg = g - 384; kt = gg / 16; nt = gg % 16; N = 256; }
  const int krow = kt * 32 + ((l >> 4) << 3);
  const int col  = nt * 16 + (l & 15);
  short v[8];
#pragma unroll
  for (int j = 0; j < 8; ++j)
    v[j] = (short)f2bf(W[(size_t)(krow + j) * N + col]);
  short* d = (g < 384) ? (W1p + ((size_t)g * 64 + l) * 8)
                       : (W2p + ((size_t)(g - 384) * 64 + l) * 8);
  *(bf16x8*)d = *(bf16x8*)v;
}

// ---------------------------------------------------------------------------
// Stage 5: MFMA decoder.  v2: 64 rows / block (was 32) — halves the per-row
// W1p/W2p B-fragment L2 traffic (18KB -> 9KB per output row), which the
// model says is the binding resource.  256 threads (4 waves); zps 64KB
// (2 blocks/CU); Hs (48KB) aliases zps; fp32 accumulate.
// ---------------------------------------------------------------------------
__global__ __launch_bounds__(256) void decoder_kernel(
    const float* __restrict__ z,  const float* __restrict__ ktab,
    const short* __restrict__ W1p, const float* __restrict__ b1,
    const short* __restrict__ W2p, const float* __restrict__ b2,
    const int* __restrict__ bi,   const int* __restrict__ ki,
    float* __restrict__ out, int T)
{
  // zps: 16 kt x 4 mt x 64 lanes x 8 bf16 = 64 KB.  Hs (48 KB) aliases it.
  __shared__ __align__(16) short zps[32768];
  __shared__ int tb[64], tk[64];

  const int tid  = threadIdx.x;
  const int wave = tid >> 6;
  const int lane = tid & 63;
  const int t0   = blockIdx.x * 64;

  if (tid < 64) {
    int t = t0 + tid;
    tb[tid] = (t < T) ? bi[t] : 0;
    tk[tid] = (t < T) ? ki[t] : 0;
  }
  __syncthreads();

  // ---- stage zp = z[b]*ktab[k] into A-fragment layout ----
  // chunk = (kt*4 + mt)*64 + lane ; element j = zp[mt*16+(lane&15)][kt*32+(lane>>4)*8+j]
#pragma unroll 4
  for (int it = 0; it < 16; ++it) {
    int chunk = tid + it * 256;
    int l  = chunk & 63;
    int mt = (chunk >> 6) & 3;
    int kt = chunk >> 8;
    int m  = mt * 16 + (l & 15);
    int k0 = kt * 32 + ((l >> 4) << 3);
    const float4* zr = (const float4*)(z    + (size_t)tb[m] * 512 + k0);
    const float4* kr = (const float4*)(ktab + (size_t)tk[m] * 512 + k0);
    float4 z0 = zr[0], z1 = zr[1], k4 = kr[0], k5 = kr[1];
    short v[8];
    v[0] = (short)f2bf(z0.x * k4.x); v[1] = (short)f2bf(z0.y * k4.y);
    v[2] = (short)f2bf(z0.z * k4.z); v[3] = (short)f2bf(z0.w * k4.w);
    v[4] = (short)f2bf(z1.x * k5.x); v[5] = (short)f2bf(z1.y * k5.y);
    v[6] = (short)f2bf(z1.z * k5.z); v[7] = (short)f2bf(z1.w * k5.w);
    *(bf16x8*)&zps[(size_t)chunk * 8] = *(bf16x8*)v;
  }
  __syncthreads();

  // ---- phase 1: H = relu(zp @ W1 + b1).  wave covers cols [96w, 96w+96) ----
  f32x4 acc[4][6];
#pragma unroll
  for (int mt = 0; mt < 4; ++mt)
#pragma unroll
    for (int j = 0; j < 6; ++j) acc[mt][j] = (f32x4){0.f, 0.f, 0.f, 0.f};

  {
    const short* wb = W1p + ((size_t)(wave * 6) * 64 + lane) * 8;
#pragma unroll 2
    for (int kt = 0; kt < 16; ++kt) {
      bf16x8 a0 = *(bf16x8*)&zps[((kt * 4 + 0) * 64 + lane) * 8];
      bf16x8 a1 = *(bf16x8*)&zps[((kt * 4 + 1) * 64 + lane) * 8];
      bf16x8 a2 = *(bf16x8*)&zps[((kt * 4 + 2) * 64 + lane) * 8];
      bf16x8 a3 = *(bf16x8*)&zps[((kt * 4 + 3) * 64 + lane) * 8];
#pragma unroll
      for (int j = 0; j < 6; ++j) {
        bf16x8 bf = *(const bf16x8*)(wb + (size_t)kt * 12288 + j * 512);
        acc[0][j] = __builtin_amdgcn_mfma_f32_16x16x32_bf16(a0, bf, acc[0][j], 0, 0, 0);
        acc[1][j] = __builtin_amdgcn_mfma_f32_16x16x32_bf16(a1, bf, acc[1][j], 0, 0, 0);
        acc[2][j] = __builtin_amdgcn_mfma_f32_16x16x32_bf16(a2, bf, acc[2][j], 0, 0, 0);
        acc[3][j] = __builtin_amdgcn_mfma_f32_16x16x32_bf16(a3, bf, acc[3][j], 0, 0, 0);
      }
    }
  }
  __syncthreads();   // all zps reads done; Hs aliases zps

  // ---- epilogue 1: bias + relu + pack into phase-2 A-fragment layout ----
  {
    short* Hs = zps;
    float bload[6];
#pragma unroll
    for (int j = 0; j < 6; ++j)
      bload[j] = b1[wave * 96 + j * 16 + (lane & 15)];
#pragma unroll
    for (int mt = 0; mt < 4; ++mt) {
#pragma unroll
      for (int j = 0; j < 6; ++j) {
        int c = wave * 96 + j * 16 + (lane & 15);
        int lane2hi = ((c >> 3) & 3) << 4;
        int ktp = (c >> 5) * 4;
        int jj = c & 7;
#pragma unroll
        for (int r = 0; r < 4; ++r) {
          int m = mt * 16 + (lane >> 4) * 4 + r;
          float v = fmaxf(acc[mt][j][r] + bload[j], 0.f);
          Hs[((ktp + (m >> 4)) * 64 + ((m & 15) | lane2hi)) * 8 + jj] = (short)f2bf(v);
        }
      }
    }
  }
  __syncthreads();

  // ---- phase 2: x = H @ W2 + b2.  wave covers cols [64w, 64w+64) ----
  f32x4 acc2[4][4];
#pragma unroll
  for (int mt = 0; mt < 4; ++mt)
#pragma unroll
    for (int j = 0; j < 4; ++j) acc2[mt][j] = (f32x4){0.f, 0.f, 0.f, 0.f};

  {
    const short* Hs = zps;
    const short* wb = W2p + ((size_t)(wave * 4) * 64 + lane) * 8;
#pragma unroll 2
    for (int kt = 0; kt < 12; ++kt) {
      bf16x8 a0 = *(const bf16x8*)&Hs[((kt * 4 + 0) * 64 + lane) * 8];
      bf16x8 a1 = *(const bf16x8*)&Hs[((kt * 4 + 1) * 64 + lane) * 8];
      bf16x8 a2 = *(const bf16x8*)&Hs[((kt * 4 + 2) * 64 + lane) * 8];
      bf16x8 a3 = *(const bf16x8*)&Hs[((kt * 4 + 3) * 64 + lane) * 8];
#pragma unroll
      for (int j = 0; j < 4; ++j) {
        bf16x8 bf = *(const bf16x8*)(wb + (size_t)kt * 8192 + j * 512);
        acc2[0][j] = __builtin_amdgcn_mfma_f32_16x16x32_bf16(a0, bf, acc2[0][j], 0, 0, 0);
        acc2[1][j] = __builtin_amdgcn_mfma_f32_16x16x32_bf16(a1, bf, acc2[1][j], 0, 0, 0);
        acc2[2][j] = __builtin_amdgcn_mfma_f32_16x16x32_bf16(a2, bf, acc2[2][j], 0, 0, 0);
        acc2[3][j] = __builtin_amdgcn_mfma_f32_16x16x32_bf16(a3, bf, acc2[3][j], 0, 0, 0);
      }
    }
  }

  // ---- epilogue 2: bias + store ----
  {
    float bload[4];
#pragma unroll
    for (int j = 0; j < 4; ++j)
      bload[j] = b2[wave * 64 + j * 16 + (lane & 15)];
#pragma unroll
    for (int mt = 0; mt < 4; ++mt) {
#pragma unroll
      for (int r = 0; r < 4; ++r) {
        int t = t0 + mt * 16 + (lane >> 4) * 4 + r;
        if (t < T) {
#pragma unroll
          for (int j = 0; j < 4; ++j) {
            int c = wave * 64 + j * 16 + (lane & 15);
            out[(size_t)t * 256 + c] = acc2[mt][j][r] + bload[j];
          }
        }
      }
    }
  }
}

// ---------------------------------------------------------------------------
extern "C" void kernel_launch(void* const* d_in, const int* in_sizes, int n_in,
                              void* d_out, int out_size, void* d_ws, size_t ws_size,
                              hipStream_t stream)
{
  const float* z      = (const float*)d_in[0];
  const float* keyW1  = (const float*)d_in[1];
  const float* keyb1  = (const float*)d_in[2];
  const float* keyg1  = (const float*)d_in[3];
  const float* keybe1 = (const float*)d_in[4];
  const float* keyW2  = (const float*)d_in[5];
  const float* keyb2  = (const float*)d_in[6];
  const float* decW1  = (const float*)d_in[7];
  const float* decb1  = (const float*)d_in[8];
  const float* decW2  = (const float*)d_in[9];
  const float* decb2  = (const float*)d_in[10];
  const float* spW1   = (const float*)d_in[11];
  const float* spb1   = (const float*)d_in[12];
  const float* spg1   = (const float*)d_in[13];
  const float* spbe1  = (const float*)d_in[14];
  const float* spW2   = (const float*)d_in[15];
  const float* spb2   = (const float*)d_in[16];

  const int T = out_size / (DIM + 1);   // out = x[T,256] ++ batch[T]

  char* ws = (char*)d_ws;
  int*   n_arr  = (int*)(ws);                 // 32768 ints
  int*   starts = (int*)(ws + 131072);        // 32769 ints
  float* ktab   = (float*)(ws + 262160);      // 17*512 f32
  short* W1p    = (short*)(ws + 296976);      // 512*384 bf16 = 393216 B
  short* W2p    = (short*)(ws + 690192);      // 384*256 bf16 = 196608 B
  int*   bi     = (int*)(ws + 886800);        // T ints
  size_t kioff  = 886800 + (((size_t)T * 4 + 15) / 16) * 16;
  int*   ki     = (int*)(ws + kioff);         // T ints

  float* outF = (float*)d_out;

  sizepred_kernel<<<B_N / 16, 320, 0, stream>>>(z, spW1, spb1, spg1, spbe1, spW2, spb2, n_arr);
  pack_kernel<<<576, 64, 0, stream>>>(decW1, decW2, W1p, W2p);
  scan_kernel<<<1, 1024, 0, stream>>>(n_arr, starts);
  keys_kernel<<<MAXN, 320, 0, stream>>>(keyW1, keyb1, keyg1, keybe1, keyW2, keyb2, ktab);
  scatter_kernel<<<B_N / 256, 256, 0, stream>>>(n_arr, starts, bi, ki, outF, T);
  if (T > 0)
    decoder_kernel<<<(T + 63) / 64, 256, 0, stream>>>(z, ktab, W1p, decb1, W2p, decb2, bi, ki, outF, T);
}